// Round 6
// baseline (4519.323 us; speedup 1.0000x reference)
//
#include <hip/hip_runtime.h>
#include <cmath>

#define S_LEN 128
#define BATCH 32
#define HID   512
#define VOCAB 10000
#define MROWS (S_LEN * BATCH)   // 4096
#define HH    (HID * HID)

#define NBLK  128
#define NTHR  512

typedef float f32x4 __attribute__((ext_vector_type(4)));

// ---------------------------------------------------------------------------
// 128x128-tile fp32 GEMM, 256 threads, 8x8 microtile.
//   GATHER_A: A row m = A[tok[m], :]
//   B_KN:     B gate-blocked [g][K][512] (k-major); else B row-major [N][K]
//   C_T:      write C[n*M + m] (transposed, for axT)
// Bs columns stored quad-XOR swizzled (pq = q ^ ((q>>3)&1)) so the 16-lane
// tx*8 read pattern is bank-conflict-free (was 4-way).
// ---------------------------------------------------------------------------
template<bool GATHER_A, bool B_KN, bool C_T>
__global__ __launch_bounds__(256) void gemm128_kernel(
    const float* __restrict__ A, const int* __restrict__ tok,
    const float* __restrict__ Bmat, const float* __restrict__ bias,
    float* __restrict__ C, int M, int N, int K)
{
    __shared__ float As[16][132];
    __shared__ float Bs[16][132];
    __shared__ int   toks[128];

    const int tid = threadIdx.x;
    const int m0  = blockIdx.y * 128;
    const int n0  = blockIdx.x * 128;

    if (GATHER_A) {
        if (tid < 128) toks[tid] = tok[m0 + tid];
        __syncthreads();
    }

    const int tx = tid & 15;
    const int ty = tid >> 4;
    const int lr = tid >> 2;          // 0..63
    const int lc = (tid & 3) * 4;     // 0,4,8,12

    // phys float offsets of this thread's B column quads (logical tx*8..+7)
    const int qb   = tx << 1;
    const int bbit = (qb >> 3) & 1;
    const int bq0  = ((qb    ) ^ bbit) << 2;
    const int bq1  = ((qb + 1) ^ bbit) << 2;

    float acc[8][8] = {};

    for (int k0 = 0; k0 < K; k0 += 16) {
        #pragma unroll
        for (int rep = 0; rep < 2; rep++) {
            int r = lr + rep * 64;
            const float* arow = GATHER_A ? A + (size_t)toks[r] * K
                                         : A + (size_t)(m0 + r) * K;
            float4 va = *(const float4*)(arow + k0 + lc);
            As[lc + 0][r] = va.x; As[lc + 1][r] = va.y;
            As[lc + 2][r] = va.z; As[lc + 3][r] = va.w;
        }
        if (B_KN) {
            const int g = n0 >> 9, col0 = n0 & 511;
            const float* bb = Bmat + (size_t)g * K * 512 + col0;
            const int q  = tid & 31;
            const int pq = (q ^ ((q >> 3) & 1)) << 2;
            const int bkh = tid >> 5;               // 0..7
            #pragma unroll
            for (int rep = 0; rep < 2; rep++) {
                int kk = bkh + rep * 8;
                float4 vb = *(const float4*)(bb + (size_t)(k0 + kk) * 512 + q * 4);
                *(float4*)&Bs[kk][pq] = vb;
            }
        } else {
            #pragma unroll
            for (int rep = 0; rep < 2; rep++) {
                int r = lr + rep * 64;
                int n = n0 + r;
                float4 vb = make_float4(0.f, 0.f, 0.f, 0.f);
                if (n < N) vb = *(const float4*)(Bmat + (size_t)n * K + k0 + lc);
                int q  = r >> 2;
                int pc = ((q ^ ((q >> 3) & 1)) << 2) + (r & 3);
                Bs[lc + 0][pc] = vb.x; Bs[lc + 1][pc] = vb.y;
                Bs[lc + 2][pc] = vb.z; Bs[lc + 3][pc] = vb.w;
            }
        }
        __syncthreads();
        #pragma unroll
        for (int k = 0; k < 16; k++) {
            f32x4 a0 = *(const f32x4*)&As[k][ty * 8];
            f32x4 a1 = *(const f32x4*)&As[k][ty * 8 + 4];
            f32x4 b0 = *(const f32x4*)&Bs[k][bq0];
            f32x4 b1 = *(const f32x4*)&Bs[k][bq1];
            float av[8] = {a0.x,a0.y,a0.z,a0.w,a1.x,a1.y,a1.z,a1.w};
            float bv[8] = {b0.x,b0.y,b0.z,b0.w,b1.x,b1.y,b1.z,b1.w};
            #pragma unroll
            for (int i = 0; i < 8; i++)
                #pragma unroll
                for (int j = 0; j < 8; j++)
                    acc[i][j] = fmaf(av[i], bv[j], acc[i][j]);
        }
        __syncthreads();
    }
    if (C_T) {
        #pragma unroll
        for (int j = 0; j < 8; j++) {
            int n = n0 + tx * 8 + j;
            float bn_ = bias[n];
            float4 v0 = make_float4(acc[0][j]+bn_, acc[1][j]+bn_,
                                    acc[2][j]+bn_, acc[3][j]+bn_);
            float4 v1 = make_float4(acc[4][j]+bn_, acc[5][j]+bn_,
                                    acc[6][j]+bn_, acc[7][j]+bn_);
            float* cp = C + (size_t)n * M + m0 + ty * 8;
            *(float4*)cp       = v0;
            *(float4*)(cp + 4) = v1;
        }
    } else {
        const bool full = (n0 + 128 <= N);
        #pragma unroll
        for (int i = 0; i < 8; i++) {
            int m = m0 + ty * 8 + i;
            if (full) {
                int n = n0 + tx * 8;
                float4 v0 = make_float4(acc[i][0]+bias[n+0], acc[i][1]+bias[n+1],
                                        acc[i][2]+bias[n+2], acc[i][3]+bias[n+3]);
                float4 v1 = make_float4(acc[i][4]+bias[n+4], acc[i][5]+bias[n+5],
                                        acc[i][6]+bias[n+6], acc[i][7]+bias[n+7]);
                *(float4*)&C[(size_t)m * N + n]     = v0;
                *(float4*)&C[(size_t)m * N + n + 4] = v1;
            } else {
                #pragma unroll
                for (int j = 0; j < 8; j++) {
                    int n = n0 + tx * 8 + j;
                    if (n < N) C[(size_t)m * N + n] = acc[i][j] + bias[n];
                }
            }
        }
    }
}

// ---------------------------------------------------------------------------
// Agent-coherent (LLC-direct) access: sc1 bypasses the per-XCD L2.
// ---------------------------------------------------------------------------
__device__ __forceinline__ f32x4 ldg_coh_x4(const float* p) {
    f32x4 r;
    asm volatile("global_load_dwordx4 %0, %1, off sc1"
                 : "=v"(r) : "v"(p) : "memory");
    return r;
}
__device__ __forceinline__ void stg_coh(float* p, float v) {
    asm volatile("global_store_dword %0, %1, off sc1"
                 :: "v"(p), "v"(v) : "memory");
}

// ---------------------------------------------------------------------------
// Split-phase contention-free device barrier (per-block monotonic flags).
// ---------------------------------------------------------------------------
__device__ __forceinline__ void bar_arrive(unsigned* flags, int bid, unsigned target)
{
    asm volatile("s_waitcnt vmcnt(0)" ::: "memory");
    __syncthreads();
    if (threadIdx.x == 0)
        __hip_atomic_store(&flags[bid], target, __ATOMIC_RELEASE, __HIP_MEMORY_SCOPE_AGENT);
}
__device__ __forceinline__ void bar_wait(unsigned* flags, unsigned target)
{
    if (threadIdx.x < NBLK) {
        while (__hip_atomic_load(&flags[threadIdx.x], __ATOMIC_RELAXED,
                                 __HIP_MEMORY_SCOPE_AGENT) < target)
            __builtin_amdgcn_s_sleep(1);
    }
    __syncthreads();
}

// ---------------------------------------------------------------------------
// Cooperative column-split GRU layer scan, v6: 128 blocks x 4 cols.
// Per-CU dot work halved vs v5 (64 blocks). Same phase/window structure:
// z-dot inside the v-barrier window, hseq+ax-prefetch inside the h-window.
// LDS ~130 KB: W 3x8KB, xbuf [k][b] 64KB, part 64x128 32KB, partR 16x128 8KB.
// Dots: bt=tid&7 (4 b), all 4 cols, ks=tid>>3 (64 slices, k=8/thread).
// ---------------------------------------------------------------------------
__global__ __launch_bounds__(NTHR) void scan_coop_kernel(
    const float* __restrict__ axT, const float* __restrict__ Ul,
    const float* __restrict__ h0g, float* __restrict__ hseq,
    float* __restrict__ hfin, float* __restrict__ vT,
    float* __restrict__ hxT, unsigned* __restrict__ flags)
{
    __shared__ float Wr[HID * 4];      //  8 KB [k][c]
    __shared__ float Wz[HID * 4];
    __shared__ float Wh[HID * 4];
    __shared__ float xbuf[HID * 32];   // 64 KB [k][b]
    __shared__ float part[64 * 128];   // 32 KB [slice][c*32+b]
    __shared__ float partR[16 * 128];  //  8 KB
    __shared__ float zbuf[4 * 33];
    __shared__ float hsave[4 * 33];
    __shared__ float hnb[4 * 33];

    const int tid = threadIdx.x;
    const int bid = blockIdx.x;
    const int ch0 = bid << 2;          // owned 4 hidden columns

    const int bt   = tid & 7;          // b0 = bt*4
    const int ks   = tid >> 3;         // 0..63, k in [ks*8, ks*8+8)
    const int out4 = tid & 31;         // reduce stage1 output quad
    const int qh   = tid >> 5;         // 0..15
    const int rc   = tid >> 5;         // act phase (tid<128): col 0..3
    const int rb   = tid & 31;         // act phase: batch

    // ---- one-time: weights into LDS ----
    for (int idx = tid; idx < HID * 4; idx += NTHR) {
        int c = idx & 3, k = idx >> 2;
        Wr[idx] = Ul[                 (size_t)k * HID + ch0 + c];
        Wz[idx] = Ul[(size_t)1 * HH + (size_t)k * HID + ch0 + c];
        Wh[idx] = Ul[(size_t)2 * HH + (size_t)k * HID + ch0 + c];
    }

    // ---- prefill hxT with h0 (own 4 rows) ----
    if (tid < 128)
        stg_coh(hxT + (ch0 + rc) * 32 + rb, h0g[rb * HID + ch0 + rc]);
    unsigned bc = 1;
    bar_arrive(flags, bid, bc);

    // ---- ax prefetch for t=0 (coalesced rows of axT) ----
    float axr = 0.f, axz = 0.f, axh = 0.f;
    if (tid < 128) {
        axr = axT[(size_t)(       ch0 + rc) * MROWS + rb];
        axz = axT[(size_t)( 512 + ch0 + rc) * MROWS + rb];
        axh = axT[(size_t)(1024 + ch0 + rc) * MROWS + rb];
    }
    bar_wait(flags, bc); bc++;

#define DOT(W) {                                                          \
    f32x4 a0 = {0.f,0.f,0.f,0.f}, a1 = a0, a2 = a0, a3 = a0;              \
    const float* wb = (W) + (ks << 5);                                    \
    const float* xb = xbuf + (ks << 8) + (bt << 2);                       \
    _Pragma("unroll")                                                     \
    for (int kk = 0; kk < 8; kk++) {                                      \
        f32x4 wv = *(const f32x4*)(wb + (kk << 2));                       \
        f32x4 xv = *(const f32x4*)(xb + (kk << 5));                       \
        a0 += wv.x * xv; a1 += wv.y * xv;                                 \
        a2 += wv.z * xv; a3 += wv.w * xv;                                 \
    }                                                                     \
    float* pp = part + (ks << 7) + (bt << 2);                             \
    *(f32x4*)(pp     ) = a0;                                              \
    *(f32x4*)(pp + 32) = a1;                                              \
    *(f32x4*)(pp + 64) = a2;                                              \
    *(f32x4*)(pp + 96) = a3; }

#define RED1 {                                                            \
    f32x4 s = {0.f,0.f,0.f,0.f};                                          \
    _Pragma("unroll")                                                     \
    for (int jj = 0; jj < 4; jj++)                                        \
        s += *(const f32x4*)&part[(((qh << 2) + jj) << 7) + (out4 << 2)]; \
    *(f32x4*)&partR[(qh << 7) + (out4 << 2)] = s; }

#define RED2(dst) {                                                       \
    float s_ = 0.f;                                                       \
    _Pragma("unroll")                                                     \
    for (int q_ = 0; q_ < 16; q_++) s_ += partR[(q_ << 7) + tid];         \
    dst = s_; }

#define STAGE(src) {                                                      \
    f32x4 ld[8];                                                          \
    _Pragma("unroll")                                                     \
    for (int i = 0; i < 8; i++)                                           \
        ld[i] = ldg_coh_x4((src) + (size_t)(tid + i * NTHR) * 4);         \
    asm volatile("s_waitcnt vmcnt(0)" ::: "memory");                      \
    _Pragma("unroll")                                                     \
    for (int i = 0; i < 8; i++)                                           \
        *(f32x4*)&xbuf[(tid + i * NTHR) * 4] = ld[i]; }

    for (int t = 0; t < S_LEN; t++) {
        // ---- stage xbuf = h(t-1) ----
        STAGE(hxT);
        __syncthreads();

        // ---- r dot + reduce + sigmoid; publish v = r*h ----
        DOT(Wr);
        __syncthreads();
        RED1;
        __syncthreads();
        if (tid < 128) {
            float s; RED2(s);
            float sig = 1.f / (1.f + __expf(-(axr + s)));
            float hk  = xbuf[((ch0 + rc) << 5) + rb];
            stg_coh(vT + (ch0 + rc) * 32 + rb, sig * hk);
        }
        bar_arrive(flags, bid, bc);

        // ================= inside v-barrier window: z gate =================
        DOT(Wz);
        __syncthreads();
        RED1;
        __syncthreads();
        if (tid < 128) {
            float s; RED2(s);
            zbuf[rc * 33 + rb]  = 1.f / (1.f + __expf(-(axz + s)));
            hsave[rc * 33 + rb] = xbuf[((ch0 + rc) << 5) + rb];
        }
        // ===================================================================
        bar_wait(flags, bc); bc++;

        // ---- stage xbuf = v ----
        STAGE(vT);
        __syncthreads();

        // ---- h_hat dot + reduce + tanh + blend; publish h ----
        DOT(Wh);
        __syncthreads();
        RED1;
        __syncthreads();
        if (tid < 128) {
            float s; RED2(s);
            float pre = axh + s;
            float e2  = __expf(2.f * pre);
            float hh  = 1.f - 2.f / (e2 + 1.f);       // tanh
            float z   = zbuf[rc * 33 + rb];
            float h   = hsave[rc * 33 + rb];
            float hn  = (1.f - z) * h + z * hh;
            stg_coh(hxT + (ch0 + rc) * 32 + rb, hn);
            hnb[rc * 33 + rb] = hn;
            if (t == S_LEN - 1) hfin[rb * HID + ch0 + rc] = hn;
        }
        bar_arrive(flags, bid, bc);

        // ============ inside h-barrier window: hseq + ax prefetch ==========
        if (tid < 128) {
            const int c2 = tid & 3, b2 = tid >> 2;
            hseq[(size_t)((t << 5) + b2) * HID + ch0 + c2] = hnb[c2 * 33 + b2];
            if (t + 1 < S_LEN) {
                const size_t o = (size_t)((t + 1) << 5) + rb;
                axr = axT[(size_t)(       ch0 + rc) * MROWS + o];
                axz = axT[(size_t)( 512 + ch0 + rc) * MROWS + o];
                axh = axT[(size_t)(1024 + ch0 + rc) * MROWS + o];
            }
        }
        // ===================================================================
        bar_wait(flags, bc); bc++;
    }
#undef DOT
#undef RED1
#undef RED2
#undef STAGE
}

// ---------------------------------------------------------------------------
extern "C" void kernel_launch(void* const* d_in, const int* in_sizes, int n_in,
                              void* d_out, int out_size, void* d_ws, size_t ws_size,
                              hipStream_t stream)
{
    const int*   tokens = (const int*)  d_in[0];   // [S,B]
    const float* h0     = (const float*)d_in[1];   // [L,B,H]
    const float* emb    = (const float*)d_in[2];   // [V,H]
    const float* Wx     = (const float*)d_in[3];   // [L,3,H,H]
    const float* bx     = (const float*)d_in[4];   // [L,3,H]
    const float* U      = (const float*)d_in[5];   // [L,3,H,H]
    const float* Wy     = (const float*)d_in[6];   // [V,H]
    const float* by     = (const float*)d_in[7];   // [V]
    float*       out    = (float*)d_out;

    // workspace: axT [1536*4096] (transposed); hseq [4096*512]
    float* ws    = (float*)d_ws;
    float* axT   = ws;
    float* hseq  = axT + (size_t)1536 * MROWS;

    const size_t logits_sz = (size_t)MROWS * VOCAB;
    float* hfin0 = out + logits_sz;
    float* hfin1 = out + logits_sz + BATCH * HID;

    // scratch carved from the logits region (overwritten by the final GEMM):
    float*    vT    = out;                         // [512][32]
    float*    hxT   = out + 16384;                 // [512][32]
    unsigned* flags = (unsigned*)(out + 32768);    // 2 x 128
    hipMemsetAsync(flags, 0, 2 * NBLK * sizeof(unsigned), stream);

    // axT0 = (emb[tokens] @ Wx[0] + bx[0])^T   [1536][4096]
    gemm128_kernel<true, true, true><<<dim3(1536 / 128, MROWS / 128), 256, 0, stream>>>(
        emb, tokens, Wx, bx, axT, MROWS, 1536, HID);

    // layer-0 scan
    scan_coop_kernel<<<NBLK, NTHR, 0, stream>>>(
        axT, U, h0, hseq, hfin0, vT, hxT, flags);

    // axT1 = (hseq @ Wx[1] + bx[1])^T
    gemm128_kernel<false, true, true><<<dim3(1536 / 128, MROWS / 128), 256, 0, stream>>>(
        hseq, nullptr, Wx + 3 * HH, bx + 1536, axT, MROWS, 1536, HID);

    // layer-1 scan
    scan_coop_kernel<<<NBLK, NTHR, 0, stream>>>(
        axT, U + 3 * HH, h0 + BATCH * HID, hseq, hfin1, vT, hxT, flags + NBLK);

    // logits = tops @ Wy^T + by
    gemm128_kernel<false, false, false><<<dim3((VOCAB + 127) / 128, MROWS / 128), 256, 0, stream>>>(
        hseq, nullptr, Wy, by, out, MROWS, VOCAB, HID);
}

// Round 8
// 4020.920 us; speedup vs baseline: 1.1240x; 1.1240x over previous
//
#include <hip/hip_runtime.h>
#include <cmath>

#define S_LEN 128
#define BATCH 32
#define HID   512
#define VOCAB 10000
#define MROWS (S_LEN * BATCH)   // 4096
#define HH    (HID * HID)

#define NBLK  64
#define NTHR  512

typedef float f32x4 __attribute__((ext_vector_type(4)));

// ---------------------------------------------------------------------------
// 128x128-tile fp32 GEMM, 256 threads, 8x8 microtile (R6-proven, unchanged).
// ---------------------------------------------------------------------------
template<bool GATHER_A, bool B_KN, bool C_T>
__global__ __launch_bounds__(256) void gemm128_kernel(
    const float* __restrict__ A, const int* __restrict__ tok,
    const float* __restrict__ Bmat, const float* __restrict__ bias,
    float* __restrict__ C, int M, int N, int K)
{
    __shared__ float As[16][132];
    __shared__ float Bs[16][132];
    __shared__ int   toks[128];

    const int tid = threadIdx.x;
    const int m0  = blockIdx.y * 128;
    const int n0  = blockIdx.x * 128;

    if (GATHER_A) {
        if (tid < 128) toks[tid] = tok[m0 + tid];
        __syncthreads();
    }

    const int tx = tid & 15;
    const int ty = tid >> 4;
    const int lr = tid >> 2;          // 0..63
    const int lc = (tid & 3) * 4;     // 0,4,8,12

    const int qb   = tx << 1;
    const int bbit = (qb >> 3) & 1;
    const int bq0  = ((qb    ) ^ bbit) << 2;
    const int bq1  = ((qb + 1) ^ bbit) << 2;

    float acc[8][8] = {};

    for (int k0 = 0; k0 < K; k0 += 16) {
        #pragma unroll
        for (int rep = 0; rep < 2; rep++) {
            int r = lr + rep * 64;
            const float* arow = GATHER_A ? A + (size_t)toks[r] * K
                                         : A + (size_t)(m0 + r) * K;
            float4 va = *(const float4*)(arow + k0 + lc);
            As[lc + 0][r] = va.x; As[lc + 1][r] = va.y;
            As[lc + 2][r] = va.z; As[lc + 3][r] = va.w;
        }
        if (B_KN) {
            const int g = n0 >> 9, col0 = n0 & 511;
            const float* bb = Bmat + (size_t)g * K * 512 + col0;
            const int q  = tid & 31;
            const int pq = (q ^ ((q >> 3) & 1)) << 2;
            const int bkh = tid >> 5;               // 0..7
            #pragma unroll
            for (int rep = 0; rep < 2; rep++) {
                int kk = bkh + rep * 8;
                float4 vb = *(const float4*)(bb + (size_t)(k0 + kk) * 512 + q * 4);
                *(float4*)&Bs[kk][pq] = vb;
            }
        } else {
            #pragma unroll
            for (int rep = 0; rep < 2; rep++) {
                int r = lr + rep * 64;
                int n = n0 + r;
                float4 vb = make_float4(0.f, 0.f, 0.f, 0.f);
                if (n < N) vb = *(const float4*)(Bmat + (size_t)n * K + k0 + lc);
                int q  = r >> 2;
                int pc = ((q ^ ((q >> 3) & 1)) << 2) + (r & 3);
                Bs[lc + 0][pc] = vb.x; Bs[lc + 1][pc] = vb.y;
                Bs[lc + 2][pc] = vb.z; Bs[lc + 3][pc] = vb.w;
            }
        }
        __syncthreads();
        #pragma unroll
        for (int k = 0; k < 16; k++) {
            f32x4 a0 = *(const f32x4*)&As[k][ty * 8];
            f32x4 a1 = *(const f32x4*)&As[k][ty * 8 + 4];
            f32x4 b0 = *(const f32x4*)&Bs[k][bq0];
            f32x4 b1 = *(const f32x4*)&Bs[k][bq1];
            float av[8] = {a0.x,a0.y,a0.z,a0.w,a1.x,a1.y,a1.z,a1.w};
            float bv[8] = {b0.x,b0.y,b0.z,b0.w,b1.x,b1.y,b1.z,b1.w};
            #pragma unroll
            for (int i = 0; i < 8; i++)
                #pragma unroll
                for (int j = 0; j < 8; j++)
                    acc[i][j] = fmaf(av[i], bv[j], acc[i][j]);
        }
        __syncthreads();
    }
    if (C_T) {
        #pragma unroll
        for (int j = 0; j < 8; j++) {
            int n = n0 + tx * 8 + j;
            float bn_ = bias[n];
            float4 v0 = make_float4(acc[0][j]+bn_, acc[1][j]+bn_,
                                    acc[2][j]+bn_, acc[3][j]+bn_);
            float4 v1 = make_float4(acc[4][j]+bn_, acc[5][j]+bn_,
                                    acc[6][j]+bn_, acc[7][j]+bn_);
            float* cp = C + (size_t)n * M + m0 + ty * 8;
            *(float4*)cp       = v0;
            *(float4*)(cp + 4) = v1;
        }
    } else {
        const bool full = (n0 + 128 <= N);
        #pragma unroll
        for (int i = 0; i < 8; i++) {
            int m = m0 + ty * 8 + i;
            if (full) {
                int n = n0 + tx * 8;
                float4 v0 = make_float4(acc[i][0]+bias[n+0], acc[i][1]+bias[n+1],
                                        acc[i][2]+bias[n+2], acc[i][3]+bias[n+3]);
                float4 v1 = make_float4(acc[i][4]+bias[n+4], acc[i][5]+bias[n+5],
                                        acc[i][6]+bias[n+6], acc[i][7]+bias[n+7]);
                *(float4*)&C[(size_t)m * N + n]     = v0;
                *(float4*)&C[(size_t)m * N + n + 4] = v1;
            } else {
                #pragma unroll
                for (int j = 0; j < 8; j++) {
                    int n = n0 + tx * 8 + j;
                    if (n < N) C[(size_t)m * N + n] = acc[i][j] + bias[n];
                }
            }
        }
    }
}

// ---------------------------------------------------------------------------
// Agent-coherent (LLC-direct) access: sc1 bypasses the per-XCD L2.
// ---------------------------------------------------------------------------
__device__ __forceinline__ f32x4 ldg_coh_x4(const float* p) {
    f32x4 r;
    asm volatile("global_load_dwordx4 %0, %1, off sc1"
                 : "=v"(r) : "v"(p) : "memory");
    return r;
}
__device__ __forceinline__ void stg_coh(float* p, float v) {
    asm volatile("global_store_dword %0, %1, off sc1"
                 :: "v"(p), "v"(v) : "memory");
}

// ---------------------------------------------------------------------------
// Split-phase contention-free device barrier (per-block monotonic flags).
// (v5-proven protocol — do not touch.)
// ---------------------------------------------------------------------------
__device__ __forceinline__ void bar_arrive(unsigned* flags, int bid, unsigned target)
{
    asm volatile("s_waitcnt vmcnt(0)" ::: "memory");
    __syncthreads();
    if (threadIdx.x == 0)
        __hip_atomic_store(&flags[bid], target, __ATOMIC_RELEASE, __HIP_MEMORY_SCOPE_AGENT);
}
__device__ __forceinline__ void bar_wait(unsigned* flags, unsigned target)
{
    if (threadIdx.x < NBLK) {
        while (__hip_atomic_load(&flags[threadIdx.x], __ATOMIC_RELAXED,
                                 __HIP_MEMORY_SCOPE_AGENT) < target)
            __builtin_amdgcn_s_sleep(1);
    }
    __syncthreads();
}

// ---------------------------------------------------------------------------
// Cooperative column-split GRU layer scan, v8 (= proven v5 + shfl-reduce).
//   - Sync protocol, STAGE, phase windows: v5 verbatim (measured 1315 us).
//   - Reduce: 2-round __shfl_xor(16/32) collapses the wave-local k-slices
//     in-register (lane bits 4-5 = ks&3); 16 lanes/wave write 8 KB part2;
//     ONE sync then the activation sums 8 wave-partials.  Replaces the
//     two-stage part/partR reduce (2 syncs + 64 KB traffic per dot-round).
//   - z/h carried in registers across phases.
// ---------------------------------------------------------------------------
__global__ __launch_bounds__(NTHR) void scan_coop_kernel(
    const float* __restrict__ axT, const float* __restrict__ Ul,
    const float* __restrict__ h0g, float* __restrict__ hseq,
    float* __restrict__ hfin, float* __restrict__ vT,
    float* __restrict__ hxT, unsigned* __restrict__ flags)
{
    __shared__ float Wr[512 * 8];      // 16 KB each, chunk-swizzled by k>>4
    __shared__ float Wz[512 * 8];
    __shared__ float Wh[512 * 8];
    __shared__ float xbuf[512 * 32];   // 64 KB [k][b], linear
    __shared__ float part2[8 * 256];   //  8 KB [wave][8c x 32b]
    __shared__ float hnb[8 * 33];

    const int tid = threadIdx.x;
    const int bid = blockIdx.x;
    const int ch0 = bid << 3;          // owned 8 hidden columns

    const int bt   = tid & 7;          // b0 = bt*4
    const int ct1  = (tid >> 3) & 1;   // c0 = ct1*4
    const int ks   = tid >> 4;         // 0..31, k in [ks*16, ks*16+16)
    const int wsel = ((ct1 ^ ks) & 1) << 2;   // swizzled weight chunk
    const int lane = tid & 63;
    const int wv   = tid >> 6;         // wave 0..7
    const int rc   = tid >> 5;         // act phase (tid<256): col 0..7
    const int rb   = tid & 31;         // act phase: batch

    // ---- one-time: weights into LDS (chunk-XOR swizzle by k>>4) ----
    for (int idx = tid; idx < 512 * 8; idx += NTHR) {
        int c = idx & 7, k = idx >> 3;
        int p = (k << 3) + ((((c >> 2) ^ (k >> 4)) & 1) << 2) + (c & 3);
        Wr[p] = Ul[                (size_t)k * HID + ch0 + c];
        Wz[p] = Ul[(size_t)1 * HH + (size_t)k * HID + ch0 + c];
        Wh[p] = Ul[(size_t)2 * HH + (size_t)k * HID + ch0 + c];
    }

    // ---- prefill hxT with h0 (own 8 rows) ----
    if (tid < 256)
        stg_coh(hxT + ((ch0 + rc) << 5) + rb, h0g[rb * HID + ch0 + rc]);
    unsigned bc = 1;
    bar_arrive(flags, bid, bc);

    // ---- ax prefetch for t=0 (coalesced rows of axT) ----
    float axr = 0.f, axz = 0.f, axh = 0.f;
    if (tid < 256) {
        axr = axT[(size_t)(       ch0 + rc) * MROWS + rb];
        axz = axT[(size_t)( 512 + ch0 + rc) * MROWS + rb];
        axh = axT[(size_t)(1024 + ch0 + rc) * MROWS + rb];
    }
    bar_wait(flags, bc); bc++;

#define STAGE(src) {                                                      \
    f32x4 ld[8];                                                          \
    _Pragma("unroll")                                                     \
    for (int i = 0; i < 8; i++)                                           \
        ld[i] = ldg_coh_x4((src) + (size_t)(tid + i * NTHR) * 4);         \
    asm volatile("s_waitcnt vmcnt(0)" ::: "memory");                      \
    _Pragma("unroll")                                                     \
    for (int i = 0; i < 8; i++)                                           \
        *(f32x4*)&xbuf[(tid + i * NTHR) * 4] = ld[i]; }

// dot + in-wave k-slice reduce + part2 write + 1 sync
#define WR4(v, m) { v.x += __shfl_xor(v.x, m); v.y += __shfl_xor(v.y, m); \
                    v.z += __shfl_xor(v.z, m); v.w += __shfl_xor(v.w, m); }
#define DOTR(W) {                                                         \
    f32x4 a0 = {0.f,0.f,0.f,0.f}, a1 = a0, a2 = a0, a3 = a0;              \
    const int kb = ks << 4;                                               \
    _Pragma("unroll")                                                     \
    for (int kk = 0; kk < 16; kk++) {                                     \
        int k = kb + kk;                                                  \
        f32x4 w4 = *(const f32x4*)&(W)[(k << 3) + wsel];                  \
        f32x4 xv = *(const f32x4*)&xbuf[(k << 5) + (bt << 2)];            \
        a0 += w4.x * xv; a1 += w4.y * xv;                                 \
        a2 += w4.z * xv; a3 += w4.w * xv;                                 \
    }                                                                     \
    WR4(a0, 16); WR4(a1, 16); WR4(a2, 16); WR4(a3, 16);                   \
    WR4(a0, 32); WR4(a1, 32); WR4(a2, 32); WR4(a3, 32);                   \
    if (lane < 16) {                                                      \
        const int c0 = ct1 << 2;                                          \
        float* pp = part2 + (wv << 8) + (bt << 2);                        \
        *(f32x4*)(pp + ((c0    ) << 5)) = a0;                             \
        *(f32x4*)(pp + ((c0 + 1) << 5)) = a1;                             \
        *(f32x4*)(pp + ((c0 + 2) << 5)) = a2;                             \
        *(f32x4*)(pp + ((c0 + 3) << 5)) = a3;                             \
    }                                                                     \
    __syncthreads(); }

// sum the 8 wave-partials for (rc, rb)
#define RSUM(dst) {                                                       \
    float s_ = 0.f;                                                       \
    _Pragma("unroll")                                                     \
    for (int w_ = 0; w_ < 8; w_++) s_ += part2[(w_ << 8) + tid];          \
    dst = s_; }

    float h_own = 0.f, z_own = 0.f;

    for (int t = 0; t < S_LEN; t++) {
        // ---- stage xbuf = h(t-1) ----
        STAGE(hxT);
        __syncthreads();

        // ---- r dot + reduce + sigmoid; publish v = r*h ----
        DOTR(Wr);
        if (tid < 256) {
            float s; RSUM(s);
            float sig = 1.f / (1.f + __expf(-(axr + s)));
            h_own = xbuf[((ch0 + rc) << 5) + rb];
            stg_coh(vT + ((ch0 + rc) << 5) + rb, sig * h_own);
        }
        bar_arrive(flags, bid, bc);

        // ================= inside v-window: z gate (reads xbuf=h) ==========
        DOTR(Wz);
        if (tid < 256) {
            float s; RSUM(s);
            z_own = 1.f / (1.f + __expf(-(axz + s)));
        }
        // ===================================================================
        bar_wait(flags, bc); bc++;

        // ---- stage xbuf = v ----
        STAGE(vT);
        __syncthreads();

        // ---- h_hat dot + reduce + tanh + blend; publish h ----
        DOTR(Wh);
        if (tid < 256) {
            float s; RSUM(s);
            float pre = axh + s;
            float e2  = __expf(2.f * pre);
            float hh  = 1.f - 2.f / (e2 + 1.f);       // tanh
            float hn  = (1.f - z_own) * h_own + z_own * hh;
            stg_coh(hxT + ((ch0 + rc) << 5) + rb, hn);
            hnb[rc * 33 + rb] = hn;
            if (t == S_LEN - 1) hfin[rb * HID + ch0 + rc] = hn;
        }
        bar_arrive(flags, bid, bc);

        // ============ inside h-window: hseq write + ax prefetch ============
        if (tid < 256) {
            const int c2 = tid & 7, b2 = tid >> 3;
            hseq[(size_t)((t << 5) + b2) * HID + ch0 + c2] = hnb[c2 * 33 + b2];
            if (t + 1 < S_LEN) {
                const size_t o = (size_t)((t + 1) << 5) + rb;
                axr = axT[(size_t)(       ch0 + rc) * MROWS + o];
                axz = axT[(size_t)( 512 + ch0 + rc) * MROWS + o];
                axh = axT[(size_t)(1024 + ch0 + rc) * MROWS + o];
            }
        }
        // ===================================================================
        bar_wait(flags, bc); bc++;
    }
#undef STAGE
#undef WR4
#undef DOTR
#undef RSUM
}

// ---------------------------------------------------------------------------
extern "C" void kernel_launch(void* const* d_in, const int* in_sizes, int n_in,
                              void* d_out, int out_size, void* d_ws, size_t ws_size,
                              hipStream_t stream)
{
    const int*   tokens = (const int*)  d_in[0];   // [S,B]
    const float* h0     = (const float*)d_in[1];   // [L,B,H]
    const float* emb    = (const float*)d_in[2];   // [V,H]
    const float* Wx     = (const float*)d_in[3];   // [L,3,H,H]
    const float* bx     = (const float*)d_in[4];   // [L,3,H]
    const float* U      = (const float*)d_in[5];   // [L,3,H,H]
    const float* Wy     = (const float*)d_in[6];   // [V,H]
    const float* by     = (const float*)d_in[7];   // [V]
    float*       out    = (float*)d_out;

    // workspace: axT [1536*4096] (transposed); hseq [4096*512]
    float* ws    = (float*)d_ws;
    float* axT   = ws;
    float* hseq  = axT + (size_t)1536 * MROWS;

    const size_t logits_sz = (size_t)MROWS * VOCAB;
    float* hfin0 = out + logits_sz;
    float* hfin1 = out + logits_sz + BATCH * HID;

    // scratch carved from the logits region (overwritten by the final GEMM):
    float*    vT    = out;                         // [512][32]
    float*    hxT   = out + 16384;                 // [512][32]
    unsigned* flags = (unsigned*)(out + 32768);    // 2 x 64
    hipMemsetAsync(flags, 0, 2 * NBLK * sizeof(unsigned), stream);

    // axT0 = (emb[tokens] @ Wx[0] + bx[0])^T   [1536][4096]
    gemm128_kernel<true, true, true><<<dim3(1536 / 128, MROWS / 128), 256, 0, stream>>>(
        emb, tokens, Wx, bx, axT, MROWS, 1536, HID);

    // layer-0 scan
    scan_coop_kernel<<<NBLK, NTHR, 0, stream>>>(
        axT, U, h0, hseq, hfin0, vT, hxT, flags);

    // axT1 = (hseq @ Wx[1] + bx[1])^T
    gemm128_kernel<false, true, true><<<dim3(1536 / 128, MROWS / 128), 256, 0, stream>>>(
        hseq, nullptr, Wx + 3 * HH, bx + 1536, axT, MROWS, 1536, HID);

    // layer-1 scan
    scan_coop_kernel<<<NBLK, NTHR, 0, stream>>>(
        axT, U + 3 * HH, h0 + BATCH * HID, hseq, hfin1, vT, hxT, flags + NBLK);

    // logits = tops @ Wy^T + by
    gemm128_kernel<false, false, false><<<dim3((VOCAB + 127) / 128, MROWS / 128), 256, 0, stream>>>(
        hseq, nullptr, Wy, by, out, MROWS, VOCAB, HID);
}